// Round 4
// baseline (889.076 us; speedup 1.0000x reference)
//
#include <hip/hip_runtime.h>

#define N_DIM 12288
#define D_DIM 16
#define TILE  256
#define NTILE (N_DIM / TILE)                         // 48
#define BM_BYTES ((size_t)N_DIM * N_DIM / 8)         // 18,874,368
#define PART_OFF (32u << 20)                         // partials at d_ws+32MB

typedef float f4 __attribute__((ext_vector_type(4)));

// out[0] = 0 (d_out is poisoned 0xAA before every timed call)
__global__ void zero_kernel(float* __restrict__ out) {
    out[0] = 0.0f;
}

// lmbd1 * (sum|U1| + sum|U2|)
__global__ void l1_kernel(const float* __restrict__ U1,
                          const float* __restrict__ U2,
                          const float* __restrict__ lmbd,
                          float* __restrict__ out) {
    const int M = N_DIM * D_DIM;
    int idx = blockIdx.x * blockDim.x + threadIdx.x;
    int stride = gridDim.x * blockDim.x;
    float s = 0.0f;
    for (int i = idx; i < M; i += stride)
        s += fabsf(U1[i]) + fabsf(U2[i]);
    #pragma unroll
    for (int off = 32; off; off >>= 1)
        s += __shfl_down(s, off, 64);
    __shared__ float ws[4];
    int lane = threadIdx.x & 63;
    int wave = threadIdx.x >> 6;
    if (lane == 0) ws[wave] = s;
    __syncthreads();
    if (threadIdx.x == 0)
        atomicAdd(out, lmbd[0] * (ws[0] + ws[1] + ws[2] + ws[3]));
}

// PASS 1: sequential stream of A (the proven full-BW pattern) -> 1-bit/elem
// bitmap. A values are EXACTLY 0.0f or 1.0f; bit = (asuint(v)>>29)&1
// (0x3F800000>>29 = 1). Byte b covers floats [8b, 8b+8): lane byte-stride 32B,
// two dwordx4 loads per byte -> every 64B line touched by consecutive lanes.
__global__ __launch_bounds__(256, 8)
void pack_kernel(const float* __restrict__ A, unsigned char* __restrict__ bm) {
    size_t idx = (size_t)blockIdx.x * blockDim.x + threadIdx.x;
    size_t stride = (size_t)gridDim.x * blockDim.x;
    #pragma unroll 4
    for (size_t b = idx; b < BM_BYTES; b += stride) {
        const uint4* p = (const uint4*)(A + b * 8);
        uint4 x = p[0], y = p[1];
        unsigned v =  ((x.x >> 29) & 1u)        | (((x.y >> 29) & 1u) << 1)
                   | (((x.z >> 29) & 1u) << 2)  | (((x.w >> 29) & 1u) << 3)
                   | (((y.x >> 29) & 1u) << 4)  | (((y.y >> 29) & 1u) << 5)
                   | (((y.z >> 29) & 1u) << 6)  | (((y.w >> 29) & 1u) << 7);
        bm[b] = (unsigned char)v;
    }
}

// PASS 2: sum_ij A_ij * (-log_sigmoid(<U1_i,U2_j>)) from the BITMAP.
// Identical arithmetic to the round-3 kernel (a reconstructed as exact
// 0.0f/1.0f -> same fmaf/product/log grouping -> bit-identical result),
// but the hot loop has ZERO global loads: tile bitmap (8 KB) in LDS,
// U1 on the wave-uniform scalar path, U2 in registers.
__global__ __launch_bounds__(256, 4)
void loss_kernel(const unsigned char* __restrict__ bm,
                 const float* __restrict__ U1,
                 const float* __restrict__ U2,
                 float* __restrict__ partials) {
    const int t    = threadIdx.x;
    const int lane = t & 63;
    const int wave = t >> 6;
    const int r0   = blockIdx.y * TILE;
    const int c0   = blockIdx.x * TILE;

    __shared__ unsigned char bmt[TILE * (TILE / 8)];   // 256 rows x 32 B = 8 KB

    // Stage tile bitmap: thread t -> row t (32 B = 2 x uint4 from L2/L3).
    {
        const uint4* src = (const uint4*)(bm + (size_t)(r0 + t) * (N_DIM / 8)
                                             + (size_t)(c0 / 8));
        uint4* dst = (uint4*)(bmt + t * 32);
        dst[0] = src[0];
        dst[1] = src[1];
    }

    // U2 fragment: 4 columns x 16 k in 64 VGPRs (coalesced f4 loads).
    float u2r[4][D_DIM];
    #pragma unroll
    for (int c = 0; c < 4; ++c) {
        const f4* p = (const f4*)(U2 + (size_t)(c0 + lane * 4 + c) * D_DIM);
        f4 qa = p[0], qb = p[1], qc = p[2], qd = p[3];
        u2r[c][0]  = qa.x; u2r[c][1]  = qa.y; u2r[c][2]  = qa.z; u2r[c][3]  = qa.w;
        u2r[c][4]  = qb.x; u2r[c][5]  = qb.y; u2r[c][6]  = qb.z; u2r[c][7]  = qb.w;
        u2r[c][8]  = qc.x; u2r[c][9]  = qc.y; u2r[c][10] = qc.z; u2r[c][11] = qc.w;
        u2r[c][12] = qd.x; u2r[c][13] = qd.y; u2r[c][14] = qd.z; u2r[c][15] = qd.w;
    }

    __syncthreads();

    // Wave-uniform U1 row pointer -> scalar (s_load) path.
    const int urow0 = __builtin_amdgcn_readfirstlane(r0 + wave * 64);
    const float* __restrict__ up = U1 + (size_t)urow0 * D_DIM;

    const float L2E = 1.4426950408889634f;
    float acc = 0.0f;                  // sums log2 of per-group products

    #pragma unroll 2
    for (int g = 0; g < 32; ++g) {     // 32 groups of 2 rows
        float p0 = 1.0f, p1 = 1.0f, p2 = 1.0f, p3 = 1.0f;
        #pragma unroll
        for (int r2 = 0; r2 < 2; ++r2) {
            const int lrow = wave * 64 + 2 * g + r2;
            const float* u = up + (size_t)(2 * g + r2) * D_DIM;
            float s0 = 0.f, s1 = 0.f, s2 = 0.f, s3 = 0.f;
            #pragma unroll
            for (int k = 0; k < D_DIM; ++k) {
                float uk = u[k];               // uniform -> SGPR operand
                s0 = fmaf(uk, u2r[0][k], s0);
                s1 = fmaf(uk, u2r[1][k], s1);
                s2 = fmaf(uk, u2r[2][k], s2);
                s3 = fmaf(uk, u2r[3][k], s3);
            }
            float e0 = __builtin_amdgcn_exp2f(-L2E * s0);
            float e1 = __builtin_amdgcn_exp2f(-L2E * s1);
            float e2 = __builtin_amdgcn_exp2f(-L2E * s2);
            float e3 = __builtin_amdgcn_exp2f(-L2E * s3);
            // thread's 4 bits: byte (4*lane+c)/8 = lane>>1, nibble (lane&1)
            unsigned b8  = bmt[lrow * 32 + (lane >> 1)];
            unsigned nib = b8 >> ((lane & 1) * 4);
            float a0 = (float)( nib       & 1u);
            float a1 = (float)((nib >> 1) & 1u);
            float a2 = (float)((nib >> 2) & 1u);
            float a3 = (float)((nib >> 3) & 1u);
            p0 *= fmaf(a0, e0, 1.0f);
            p1 *= fmaf(a1, e1, 1.0f);
            p2 *= fmaf(a2, e2, 1.0f);
            p3 *= fmaf(a3, e3, 1.0f);
        }
        acc += __builtin_amdgcn_logf((p0 * p1) * (p2 * p3));  // v_log_f32=log2
    }

    float part = acc * 0.69314718055994531f;     // ln2: log2 -> ln

    // wave reduce -> block reduce -> one plain store per block (no atomic)
    #pragma unroll
    for (int off = 32; off; off >>= 1)
        part += __shfl_down(part, off, 64);
    __shared__ float wsum[4];
    if (lane == 0) wsum[wave] = part;
    __syncthreads();
    if (t == 0)
        partials[blockIdx.y * NTILE + blockIdx.x] =
            wsum[0] + wsum[1] + wsum[2] + wsum[3];
}

// Sum the 2304 block partials into out.
__global__ void reduce_kernel(const float* __restrict__ partials,
                              float* __restrict__ out) {
    const int M = NTILE * NTILE;
    float s = 0.0f;
    for (int i = threadIdx.x; i < M; i += 256)
        s += partials[i];
    #pragma unroll
    for (int off = 32; off; off >>= 1)
        s += __shfl_down(s, off, 64);
    __shared__ float wsum[4];
    int lane = threadIdx.x & 63;
    int wave = threadIdx.x >> 6;
    if (lane == 0) wsum[wave] = s;
    __syncthreads();
    if (threadIdx.x == 0)
        atomicAdd(out, wsum[0] + wsum[1] + wsum[2] + wsum[3]);
}

extern "C" void kernel_launch(void* const* d_in, const int* in_sizes, int n_in,
                              void* d_out, int out_size, void* d_ws, size_t ws_size,
                              hipStream_t stream) {
    const float* A    = (const float*)d_in[0];
    const float* U1   = (const float*)d_in[1];
    const float* U2   = (const float*)d_in[2];
    const float* lmbd = (const float*)d_in[3];
    float* out = (float*)d_out;
    unsigned char* bm = (unsigned char*)d_ws;
    float* partials   = (float*)((char*)d_ws + PART_OFF);

    zero_kernel<<<1, 64, 0, stream>>>(out);
    l1_kernel<<<256, 256, 0, stream>>>(U1, U2, lmbd, out);

    pack_kernel<<<2048, 256, 0, stream>>>(A, bm);    // sequential full-BW pass

    dim3 grid(NTILE, NTILE);                         // 48 x 48 = 2304 blocks
    loss_kernel<<<grid, 256, 0, stream>>>(bm, U1, U2, partials);
    reduce_kernel<<<1, 256, 0, stream>>>(partials, out);
}

// Round 5
// 747.694 us; speedup vs baseline: 1.1891x; 1.1891x over previous
//
#include <hip/hip_runtime.h>

#define N_DIM 12288
#define D_DIM 16
#define TILE  256               // 256x256 tile of A per block
#define NTILE (N_DIM / TILE)    // 48 -> 2304 blocks

typedef float f4 __attribute__((ext_vector_type(4)));

// out[0] = 0 (d_out is poisoned 0xAA before every timed call)
__global__ void zero_kernel(float* __restrict__ out) {
    out[0] = 0.0f;
}

// lmbd1 * (sum|U1| + sum|U2|)
__global__ void l1_kernel(const float* __restrict__ U1,
                          const float* __restrict__ U2,
                          const float* __restrict__ lmbd,
                          float* __restrict__ out) {
    const int M = N_DIM * D_DIM;
    int idx = blockIdx.x * blockDim.x + threadIdx.x;
    int stride = gridDim.x * blockDim.x;
    float s = 0.0f;
    for (int i = idx; i < M; i += stride)
        s += fabsf(U1[i]) + fabsf(U2[i]);
    #pragma unroll
    for (int off = 32; off; off >>= 1)
        s += __shfl_down(s, off, 64);
    __shared__ float ws[4];
    int lane = threadIdx.x & 63;
    int wave = threadIdx.x >> 6;
    if (lane == 0) ws[wave] = s;
    __syncthreads();
    if (threadIdx.x == 0)
        atomicAdd(out, lmbd[0] * (ws[0] + ws[1] + ws[2] + ws[3]));
}

// sum_ij A_ij * (-log_sigmoid(<U1_i,U2_j>)), single pass over A.
// Theory (r0-r4): reads of d_in are capped ~1.7 TB/s regardless of pattern
// (strided f2/f4, sequential uint4, nt or not all give ~355 us for 604 MB).
// So: ONE read of A, fused with all math; maximize request size (f4) and
// in-flight depth (4-row groups, dual-buffered -> 8 nt f4 loads in flight).
// Thread owns 4 U2 columns in 64 VGPRs; U1 rows on the wave-uniform scalar
// path. A in {0,1}: A*log(1+e) == log(1+A*e); per 4-row group accumulate
// product of 16 fma(A,e,1) terms (each in [1,2), product < 2^16), ONE log2
// per group. VGPR ~116 < 128 cap of __launch_bounds__(256,4): no spill.
__global__ __launch_bounds__(256, 4)
void loss_kernel(const float* __restrict__ A,
                 const float* __restrict__ U1,
                 const float* __restrict__ U2,
                 float* __restrict__ out) {
    const int t    = threadIdx.x;
    const int lane = t & 63;
    const int wave = t >> 6;
    const int r0   = blockIdx.y * TILE;
    const int c0   = blockIdx.x * TILE;

    // U2 fragment: 4 columns x 16 k in 64 VGPRs (coalesced f4 loads;
    // wave covers a contiguous 16 KB span of U2).
    float u2r[4][D_DIM];
    #pragma unroll
    for (int c = 0; c < 4; ++c) {
        const f4* p = (const f4*)(U2 + (size_t)(c0 + lane * 4 + c) * D_DIM);
        f4 qa = p[0], qb = p[1], qc = p[2], qd = p[3];
        u2r[c][0]  = qa.x; u2r[c][1]  = qa.y; u2r[c][2]  = qa.z; u2r[c][3]  = qa.w;
        u2r[c][4]  = qb.x; u2r[c][5]  = qb.y; u2r[c][6]  = qb.z; u2r[c][7]  = qb.w;
        u2r[c][8]  = qc.x; u2r[c][9]  = qc.y; u2r[c][10] = qc.z; u2r[c][11] = qc.w;
        u2r[c][12] = qd.x; u2r[c][13] = qd.y; u2r[c][14] = qd.z; u2r[c][15] = qd.w;
    }

    // Wave-uniform U1 row pointer -> scalar (s_load) path.
    const int urow0 = __builtin_amdgcn_readfirstlane(r0 + wave * 64);
    const float* __restrict__ up = U1 + (size_t)urow0 * D_DIM;
    const float* __restrict__ ap =
        A + (size_t)(r0 + wave * 64) * N_DIM + (size_t)c0 + lane * 4;

    const float L2E = 1.4426950408889634f;
    float acc = 0.0f;                  // sums log2 of per-group products

    f4 av[4], bv[4];                   // statically indexed -> registers

#define LOADG(buf, g)                                                          \
    { _Pragma("unroll")                                                        \
      for (int r = 0; r < 4; ++r)                                              \
          buf[r] = __builtin_nontemporal_load(                                 \
              (const f4*)(ap + (size_t)(4 * (g) + r) * N_DIM)); }

#define COMPG(buf, g)                                                          \
    { float p0 = 1.0f, p1 = 1.0f, p2 = 1.0f, p3 = 1.0f;                        \
      _Pragma("unroll")                                                        \
      for (int r = 0; r < 4; ++r) {                                            \
          const float* u = up + (size_t)(4 * (g) + r) * D_DIM;                 \
          float s0 = 0.f, s1 = 0.f, s2 = 0.f, s3 = 0.f;                        \
          _Pragma("unroll")                                                    \
          for (int k = 0; k < D_DIM; ++k) {                                    \
              float uk = u[k];               /* uniform -> SGPR operand */     \
              s0 = fmaf(uk, u2r[0][k], s0);                                    \
              s1 = fmaf(uk, u2r[1][k], s1);                                    \
              s2 = fmaf(uk, u2r[2][k], s2);                                    \
              s3 = fmaf(uk, u2r[3][k], s3);                                    \
          }                                                                    \
          float e0 = __builtin_amdgcn_exp2f(-L2E * s0);                        \
          float e1 = __builtin_amdgcn_exp2f(-L2E * s1);                        \
          float e2 = __builtin_amdgcn_exp2f(-L2E * s2);                        \
          float e3 = __builtin_amdgcn_exp2f(-L2E * s3);                        \
          f4 a = buf[r];                                                       \
          p0 *= fmaf(a.x, e0, 1.0f);                                           \
          p1 *= fmaf(a.y, e1, 1.0f);                                           \
          p2 *= fmaf(a.z, e2, 1.0f);                                           \
          p3 *= fmaf(a.w, e3, 1.0f);                                           \
      }                                                                        \
      acc += __builtin_amdgcn_logf((p0 * p1) * (p2 * p3)); }  /* v_log_f32 */

    LOADG(av, 0);                       // prologue: rows 0..3
    #pragma unroll
    for (int gg = 0; gg < 8; ++gg) {    // 16 groups of 4 rows, in pairs
        LOADG(bv, 2 * gg + 1);          // prefetch next group (8 f4 in flight)
        COMPG(av, 2 * gg);
        if (gg < 7) LOADG(av, 2 * gg + 2);
        COMPG(bv, 2 * gg + 1);
    }
#undef LOADG
#undef COMPG

    float part = acc * 0.69314718055994531f;     // ln2: log2 -> ln

    // wave reduce -> block reduce -> one atomic per block
    #pragma unroll
    for (int off = 32; off; off >>= 1)
        part += __shfl_down(part, off, 64);
    __shared__ float wsum[4];
    if (lane == 0) wsum[wave] = part;
    __syncthreads();
    if (t == 0)
        atomicAdd(out, wsum[0] + wsum[1] + wsum[2] + wsum[3]);
}

extern "C" void kernel_launch(void* const* d_in, const int* in_sizes, int n_in,
                              void* d_out, int out_size, void* d_ws, size_t ws_size,
                              hipStream_t stream) {
    const float* A    = (const float*)d_in[0];
    const float* U1   = (const float*)d_in[1];
    const float* U2   = (const float*)d_in[2];
    const float* lmbd = (const float*)d_in[3];
    float* out = (float*)d_out;

    zero_kernel<<<1, 64, 0, stream>>>(out);
    l1_kernel<<<256, 256, 0, stream>>>(U1, U2, lmbd, out);

    dim3 grid(NTILE, NTILE);            // 48 x 48 = 2304 blocks
    loss_kernel<<<grid, 256, 0, stream>>>(A, U1, U2, out);
}